// Round 3
// baseline (389.957 us; speedup 1.0000x reference)
//
#include <hip/hip_runtime.h>

typedef short bf16x8 __attribute__((ext_vector_type(8)));
typedef float f32x4 __attribute__((ext_vector_type(4)));

__device__ inline float bf2f(ushort u) {
    unsigned v = ((unsigned)u) << 16;
    return __builtin_bit_cast(float, v);
}
__device__ inline ushort f2bf(float f) {
    unsigned u = __builtin_bit_cast(unsigned, f);
    u += 0x7fffu + ((u >> 16) & 1u);
    return (ushort)(u >> 16);
}
__device__ inline void async_load16(const ushort* g, ushort* l) {
    __builtin_amdgcn_global_load_lds((const __attribute__((address_space(1))) void*)g,
                                     (__attribute__((address_space(3))) void*)l, 16, 0, 0);
}

// fp32 -> bf16 cast, 8 elems/thread
__global__ void cast_f32_bf16(const float* __restrict__ src, ushort* __restrict__ dst, int n) {
    int i = (blockIdx.x * 256 + threadIdx.x) * 8;
    if (i >= n) return;
    float4 a = *(const float4*)(src + i);
    float4 b = *(const float4*)(src + i + 4);
    union { ushort u[8]; float4 v; } o;
    o.u[0] = f2bf(a.x); o.u[1] = f2bf(a.y); o.u[2] = f2bf(a.z); o.u[3] = f2bf(a.w);
    o.u[4] = f2bf(b.x); o.u[5] = f2bf(b.y); o.u[6] = f2bf(b.z); o.u[7] = f2bf(b.w);
    *(float4*)(dst + i) = o.v;
}

// Fused QKVS projection. X:[4096,1024] bf16, W*:[N,1024] bf16 row-major, bias fp32.
// blockIdx.x: 0-7 -> Q (scaled by 0.125*log2e), 8-15 -> K, 16-23 -> V (written transposed
// to VtG[bh][d][s]), 24-25 -> S (sigmoid*0.1+0.95 -> fp32 sb[4096][256]).
// m97-style: unpadded LDS, async global_load_lds width-16 staging.
__launch_bounds__(256, 3)
__global__ void fused_qkvs(const ushort* __restrict__ X,
                           const ushort* __restrict__ Wq, const ushort* __restrict__ Wk,
                           const ushort* __restrict__ Wv, const ushort* __restrict__ Ws,
                           const float* __restrict__ bq, const float* __restrict__ bk,
                           const float* __restrict__ bv, const float* __restrict__ bs,
                           ushort* __restrict__ Qb, ushort* __restrict__ Kb,
                           ushort* __restrict__ VtG, float* __restrict__ sb)
{
    __shared__ __align__(16) ushort As[128 * 64];
    __shared__ __align__(16) ushort Bs[128 * 64];
    const int tid = threadIdx.x, w = tid >> 6, lane = tid & 63;
    const int l15 = lane & 15, quad = lane >> 4;
    const int lrow = lane >> 3, lcol = (lane & 7) * 8;
    const int xb = blockIdx.x;
    const int m0 = blockIdx.y * 128;

    const ushort* W; const float* bias; int n0, mode;
    if (xb < 8)       { W = Wq; bias = bq; n0 = xb * 128;        mode = 1; }
    else if (xb < 16) { W = Wk; bias = bk; n0 = (xb - 8) * 128;  mode = 0; }
    else if (xb < 24) { W = Wv; bias = bv; n0 = (xb - 16) * 128; mode = 2; }
    else              { W = Ws; bias = bs; n0 = (xb - 24) * 128; mode = 3; }

    const int wm = (w >> 1) * 64, wn = (w & 1) * 64;

    f32x4 acc[4][4];
    for (int i = 0; i < 4; i++) for (int j = 0; j < 4; j++) acc[i][j] = (f32x4){0.f, 0.f, 0.f, 0.f};

    for (int k0 = 0; k0 < 1024; k0 += 64) {
        __syncthreads();
        for (int c = 0; c < 4; ++c) {
            int r = w * 32 + c * 8;
            async_load16(&X[(size_t)(m0 + r + lrow) * 1024 + k0 + lcol], &As[r * 64]);
            async_load16(&W[(size_t)(n0 + r + lrow) * 1024 + k0 + lcol], &Bs[r * 64]);
        }
        __syncthreads();
        for (int kk = 0; kk < 64; kk += 32) {
            bf16x8 a[4], b[4];
            for (int i = 0; i < 4; i++) a[i] = *(const bf16x8*)&As[(wm + i * 16 + l15) * 64 + kk + quad * 8];
            for (int j = 0; j < 4; j++) b[j] = *(const bf16x8*)&Bs[(wn + j * 16 + l15) * 64 + kk + quad * 8];
            for (int i = 0; i < 4; i++)
                for (int j = 0; j < 4; j++)
                    acc[i][j] = __builtin_amdgcn_mfma_f32_16x16x32_bf16(a[i], b[j], acc[i][j], 0, 0, 0);
        }
    }

    const float QSCALE = 0.125f * 1.44269504f;  // fold 1/sqrt(D) and ln->log2 into Q
    for (int i = 0; i < 4; i++) {
        for (int j = 0; j < 4; j++) {
            int gn = n0 + wn + j * 16 + l15;
            float bv_ = bias[gn];
            for (int r = 0; r < 4; r++) {
                int gm = m0 + wm + i * 16 + quad * 4 + r;
                float v = acc[i][j][r] + bv_;
                if (mode == 1) {
                    Qb[(size_t)gm * 1024 + gn] = f2bf(v * QSCALE);
                } else if (mode == 0) {
                    Kb[(size_t)gm * 1024 + gn] = f2bf(v);
                } else if (mode == 2) {
                    // transposed: VtG[bh][d][s], bh=(b)*16+h
                    size_t idx = (size_t)((gm >> 11) * 16 + (gn >> 6)) * 131072
                               + (size_t)(gn & 63) * 2048 + (gm & 2047);
                    VtG[idx] = f2bf(v);
                } else {
                    float sg = 1.0f / (1.0f + exp2f(-v * 1.44269504f));
                    sb[(size_t)gm * 256 + gn] = sg * 0.1f + 0.95f;
                }
            }
        }
    }
}

// Flash attention, no-max softmax (scores bounded; log2e folded into Q).
// Q:[4096,1024] bf16 (pre-scaled by 0.125*log2e; s applied during staging here),
// K:[4096,1024] bf16, Vt:[32][64][2048] bf16 (pre-transposed), out fp32 [4096,1024].
// grid (16, 32), block 256. One barrier per k-iter; K/V async double-buffered.
__launch_bounds__(256, 2)
__global__ void attn_kernel(const ushort* __restrict__ Q, const ushort* __restrict__ K,
                            const ushort* __restrict__ Vt, const float* __restrict__ sb,
                            float* __restrict__ out)
{
    __shared__ __align__(16) ushort Qs[128 * 72];
    __shared__ __align__(16) ushort Ps[128 * 72];
    __shared__ __align__(16) ushort Ks0[64 * 64];
    __shared__ __align__(16) ushort Ks1[64 * 64];
    __shared__ __align__(16) ushort Vs0[64 * 64];
    __shared__ __align__(16) ushort Vs1[64 * 64];

    const int tid = threadIdx.x, w = tid >> 6, lane = tid & 63;
    const int l15 = lane & 15, quad = lane >> 4;
    const int lrow = lane >> 3, lcol = (lane & 7) * 8;
    const int bh = blockIdx.y, b = bh >> 4, h = bh & 15;
    const int q0 = blockIdx.x * 128;
    const size_t rowbase = (size_t)b * 2048;
    const int cbase = h * 64;

    // stage Q tile, applying groupwise scale s (s index for col n is n>>2)
    for (int it = 0; it < 4; ++it) {
        int l = tid + it * 256;
        int r = l >> 3, c = (l & 7) * 8;
        union { float4 f; ushort u[8]; } uu, oo;
        uu.f = *(const float4*)&Q[(rowbase + q0 + r) * 1024 + cbase + c];
        const float* sp = &sb[(rowbase + q0 + r) * 256 + ((cbase + c) >> 2)];
        float s0 = sp[0], s1 = sp[1];
        for (int j = 0; j < 4; j++) oo.u[j] = f2bf(bf2f(uu.u[j]) * s0);
        for (int j = 4; j < 8; j++) oo.u[j] = f2bf(bf2f(uu.u[j]) * s1);
        *(float4*)&Qs[r * 72 + c] = oo.f;
    }

    // prefetch K/V tile 0 into buffer 0
    for (int c = 0; c < 2; ++c) {
        int r = w * 16 + c * 8;
        async_load16(&K[(rowbase + r + lrow) * 1024 + cbase + lcol], &Ks0[r * 64]);
        async_load16(&Vt[(size_t)bh * 131072 + (size_t)(r + lrow) * 2048 + lcol], &Vs0[r * 64]);
    }

    float lsum[2][4];
    f32x4 o[2][4];
    for (int mt = 0; mt < 2; mt++) for (int r = 0; r < 4; r++) lsum[mt][r] = 0.f;
    for (int mt = 0; mt < 2; mt++) for (int nt = 0; nt < 4; nt++) o[mt][nt] = (f32x4){0.f, 0.f, 0.f, 0.f};

#define ATTN_STEP(KC, VC, KN, VN, KT, PREFETCH)                                                         \
    {                                                                                                   \
        __syncthreads(); /* waves drained vmcnt: tile KT resident; buf KN/VN free */                     \
        if (PREFETCH) {                                                                                 \
            int nk = (KT) + 1;                                                                          \
            for (int c = 0; c < 2; ++c) {                                                               \
                int r = w * 16 + c * 8;                                                                 \
                async_load16(&K[(rowbase + nk * 64 + r + lrow) * 1024 + cbase + lcol], &KN[r * 64]);    \
                async_load16(&Vt[(size_t)bh * 131072 + (size_t)(r + lrow) * 2048 + nk * 64 + lcol],     \
                             &VN[r * 64]);                                                              \
            }                                                                                           \
        }                                                                                               \
        f32x4 sacc[2][4];                                                                               \
        for (int mt = 0; mt < 2; mt++)                                                                  \
            for (int nt = 0; nt < 4; nt++) sacc[mt][nt] = (f32x4){0.f, 0.f, 0.f, 0.f};                  \
        for (int kk = 0; kk < 64; kk += 32) {                                                           \
            bf16x8 a[2], bb[4];                                                                         \
            for (int mt = 0; mt < 2; mt++)                                                              \
                a[mt] = *(const bf16x8*)&Qs[(w * 32 + mt * 16 + l15) * 72 + kk + quad * 8];             \
            for (int nt = 0; nt < 4; nt++)                                                              \
                bb[nt] = *(const bf16x8*)&KC[(nt * 16 + l15) * 64 + kk + quad * 8];                     \
            for (int mt = 0; mt < 2; mt++)                                                              \
                for (int nt = 0; nt < 4; nt++)                                                          \
                    sacc[mt][nt] = __builtin_amdgcn_mfma_f32_16x16x32_bf16(a[mt], bb[nt],               \
                                                                           sacc[mt][nt], 0, 0, 0);     \
        }                                                                                               \
        for (int mt = 0; mt < 2; mt++)                                                                  \
            for (int nt = 0; nt < 4; nt++)                                                              \
                for (int r = 0; r < 4; r++) {                                                           \
                    float p = exp2f(sacc[mt][nt][r]);                                                   \
                    lsum[mt][r] += p;                                                                   \
                    Ps[(w * 32 + mt * 16 + quad * 4 + r) * 72 + nt * 16 + l15] = f2bf(p);               \
                }                                                                                       \
        /* Ps strip is wave-private: in-wave lgkmcnt ordering suffices, no barrier */                    \
        for (int kk = 0; kk < 64; kk += 32) {                                                           \
            bf16x8 a[2], bb[4];                                                                         \
            for (int mt = 0; mt < 2; mt++)                                                              \
                a[mt] = *(const bf16x8*)&Ps[(w * 32 + mt * 16 + l15) * 72 + kk + quad * 8];             \
            for (int nt = 0; nt < 4; nt++)                                                              \
                bb[nt] = *(const bf16x8*)&VC[(nt * 16 + l15) * 64 + kk + quad * 8];                     \
            for (int mt = 0; mt < 2; mt++)                                                              \
                for (int nt = 0; nt < 4; nt++)                                                          \
                    o[mt][nt] = __builtin_amdgcn_mfma_f32_16x16x32_bf16(a[mt], bb[nt],                  \
                                                                        o[mt][nt], 0, 0, 0);            \
        }                                                                                               \
    }

    for (int kt = 0; kt < 32; kt += 2) {
        ATTN_STEP(Ks0, Vs0, Ks1, Vs1, kt, 1);
        ATTN_STEP(Ks1, Vs1, Ks0, Vs0, kt + 1, (kt + 2 < 32));
    }
#undef ATTN_STEP

    // single end-of-block reduction of row sums across the 16 col-lanes
    for (int mt = 0; mt < 2; mt++)
        for (int r = 0; r < 4; r++) {
            float s = lsum[mt][r];
            for (int off = 1; off < 16; off <<= 1) s += __shfl_xor(s, off);
            lsum[mt][r] = s;
        }

    for (int mt = 0; mt < 2; mt++) {
        for (int r = 0; r < 4; r++) {
            float inv = 1.0f / lsum[mt][r];
            int q = q0 + w * 32 + mt * 16 + quad * 4 + r;
            size_t base = (rowbase + q) * 1024 + cbase;
            for (int nt = 0; nt < 4; nt++)
                out[base + nt * 16 + l15] = o[mt][nt][r] * inv;
        }
    }
}

extern "C" void kernel_launch(void* const* d_in, const int* in_sizes, int n_in,
                              void* d_out, int out_size, void* d_ws, size_t ws_size,
                              hipStream_t stream) {
    const float* hs = (const float*)d_in[0];
    const float* Wq = (const float*)d_in[1];
    const float* bq = (const float*)d_in[2];
    const float* Wk = (const float*)d_in[3];
    const float* bk = (const float*)d_in[4];
    const float* Wv = (const float*)d_in[5];
    const float* bv = (const float*)d_in[6];
    const float* Ws = (const float*)d_in[7];
    const float* bs = (const float*)d_in[8];
    float* outp = (float*)d_out;

    char* ws = (char*)d_ws;
    ushort* Qb    = (ushort*)(ws);                 //  8 MB
    ushort* Kb    = (ushort*)(ws + 8388608);       //  8 MB
    ushort* VtG   = (ushort*)(ws + 16777216);      //  8 MB (V transposed [bh][d][s])
    float*  sb    = (float* )(ws + 25165824);      //  4 MB
    ushort* hs_bf = (ushort*)(ws + 29360128);      //  8 MB
    ushort* Wq_bf = (ushort*)(ws + 37748736);      //  2 MB
    ushort* Wk_bf = (ushort*)(ws + 39845888);      //  2 MB
    ushort* Wv_bf = (ushort*)(ws + 41943040);      //  2 MB
    ushort* Ws_bf = (ushort*)(ws + 44040192);      // 0.5 MB -> total 44,564,480 B

    dim3 blk(256);
    cast_f32_bf16<<<dim3(2048), blk, 0, stream>>>(hs, hs_bf, 4194304);
    cast_f32_bf16<<<dim3(512),  blk, 0, stream>>>(Wq, Wq_bf, 1048576);
    cast_f32_bf16<<<dim3(512),  blk, 0, stream>>>(Wk, Wk_bf, 1048576);
    cast_f32_bf16<<<dim3(512),  blk, 0, stream>>>(Wv, Wv_bf, 1048576);
    cast_f32_bf16<<<dim3(128),  blk, 0, stream>>>(Ws, Ws_bf, 262144);

    fused_qkvs<<<dim3(26, 32), blk, 0, stream>>>(hs_bf, Wq_bf, Wk_bf, Wv_bf, Ws_bf,
                                                 bq, bk, bv, bs, Qb, Kb, VtG, sb);
    attn_kernel<<<dim3(16, 32), blk, 0, stream>>>(Qb, Kb, VtG, sb, outp);
}

// Round 4
// 221.673 us; speedup vs baseline: 1.7592x; 1.7592x over previous
//
#include <hip/hip_runtime.h>

typedef short bf16x8 __attribute__((ext_vector_type(8)));
typedef float f32x4 __attribute__((ext_vector_type(4)));

__device__ inline float bf2f(ushort u) {
    unsigned v = ((unsigned)u) << 16;
    return __builtin_bit_cast(float, v);
}
__device__ inline ushort f2bf(float f) {
    unsigned u = __builtin_bit_cast(unsigned, f);
    u += 0x7fffu + ((u >> 16) & 1u);
    return (ushort)(u >> 16);
}
__device__ inline void async_load16(const ushort* g, ushort* l) {
    __builtin_amdgcn_global_load_lds((const __attribute__((address_space(1))) void*)g,
                                     (__attribute__((address_space(3))) void*)l, 16, 0, 0);
}

// fp32 -> bf16 cast, 8 elems/thread
__global__ void cast_f32_bf16(const float* __restrict__ src, ushort* __restrict__ dst, int n) {
    int i = (blockIdx.x * 256 + threadIdx.x) * 8;
    if (i >= n) return;
    float4 a = *(const float4*)(src + i);
    float4 b = *(const float4*)(src + i + 4);
    union { ushort u[8]; float4 v; } o;
    o.u[0] = f2bf(a.x); o.u[1] = f2bf(a.y); o.u[2] = f2bf(a.z); o.u[3] = f2bf(a.w);
    o.u[4] = f2bf(b.x); o.u[5] = f2bf(b.y); o.u[6] = f2bf(b.z); o.u[7] = f2bf(b.w);
    *(float4*)(dst + i) = o.v;
}

// Fused QKVS projection. X:[4096,1024] bf16, W*:[N,1024] bf16 row-major, bias fp32.
// Work decode (XCD-swizzled): xb 0-7 -> Q (scaled 0.125*log2e), 8-15 -> K,
// 16-23 -> V (transposed to VtG[bh][d][s]), 24-25 -> S (sigmoid -> fp32 sb).
// Epilogue goes through LDS so all global stores are 16B/lane full-line.
__launch_bounds__(256, 3)
__global__ void fused_qkvs(const ushort* __restrict__ X,
                           const ushort* __restrict__ Wq, const ushort* __restrict__ Wk,
                           const ushort* __restrict__ Wv, const ushort* __restrict__ Ws,
                           const float* __restrict__ bq, const float* __restrict__ bk,
                           const float* __restrict__ bv, const float* __restrict__ bs,
                           ushort* __restrict__ Qb, ushort* __restrict__ Kb,
                           ushort* __restrict__ VtG, float* __restrict__ sb)
{
    __shared__ __align__(16) ushort Sm[128 * 136];   // 34,816 B; aliases As/Bs in main loop
    ushort* As = Sm;                 // 128*64
    ushort* Bs = Sm + 128 * 64;      // 128*64

    const int tid = threadIdx.x, w = tid >> 6, lane = tid & 63;
    const int l15 = lane & 15, quad = lane >> 4;
    const int lrow = lane >> 3, lcol = (lane & 7) * 8;

    // XCD swizzle: same blockIdx.y (same X tile) -> same XCD (wid % 8)
    const int wid = blockIdx.x;
    const int r8 = wid & 7, jj = wid >> 3;
    const int by = (jj & 3) * 8 + r8;    // 0..31
    const int xb = jj >> 2;              // 0..25
    const int m0 = by * 128;

    const ushort* W; const float* bias; int n0, mode;
    if (xb < 8)       { W = Wq; bias = bq; n0 = xb * 128;        mode = 1; }
    else if (xb < 16) { W = Wk; bias = bk; n0 = (xb - 8) * 128;  mode = 0; }
    else if (xb < 24) { W = Wv; bias = bv; n0 = (xb - 16) * 128; mode = 2; }
    else              { W = Ws; bias = bs; n0 = (xb - 24) * 128; mode = 3; }

    const int wm = (w >> 1) * 64, wn = (w & 1) * 64;

    f32x4 acc[4][4];
    for (int i = 0; i < 4; i++) for (int j = 0; j < 4; j++) acc[i][j] = (f32x4){0.f, 0.f, 0.f, 0.f};

    for (int k0 = 0; k0 < 1024; k0 += 64) {
        __syncthreads();
        for (int c = 0; c < 4; ++c) {
            int r = w * 32 + c * 8;
            async_load16(&X[(size_t)(m0 + r + lrow) * 1024 + k0 + lcol], &As[r * 64]);
            async_load16(&W[(size_t)(n0 + r + lrow) * 1024 + k0 + lcol], &Bs[r * 64]);
        }
        __syncthreads();
        for (int kk = 0; kk < 64; kk += 32) {
            bf16x8 a[4], b[4];
            for (int i = 0; i < 4; i++) a[i] = *(const bf16x8*)&As[(wm + i * 16 + l15) * 64 + kk + quad * 8];
            for (int j = 0; j < 4; j++) b[j] = *(const bf16x8*)&Bs[(wn + j * 16 + l15) * 64 + kk + quad * 8];
            for (int i = 0; i < 4; i++)
                for (int j = 0; j < 4; j++)
                    acc[i][j] = __builtin_amdgcn_mfma_f32_16x16x32_bf16(a[i], b[j], acc[i][j], 0, 0, 0);
        }
    }

    const float QSCALE = 0.125f * 1.44269504f;  // 1/sqrt(D) and ln->log2 folded into Q

    if (mode == 3) {
        // sb stores are 16 lanes x 4B = full 64B lines already: store direct
        for (int i = 0; i < 4; i++)
            for (int j = 0; j < 4; j++) {
                int gn = n0 + wn + j * 16 + l15;
                float bv_ = bias[gn];
                for (int r = 0; r < 4; r++) {
                    int gm = m0 + wm + i * 16 + quad * 4 + r;
                    float v = acc[i][j][r] + bv_;
                    float sg = 1.0f / (1.0f + exp2f(-v * 1.44269504f));
                    sb[(size_t)gm * 256 + gn] = sg * 0.1f + 0.95f;
                }
            }
        return;
    }

    __syncthreads();  // main loop done with As/Bs; Sm becomes epilogue scratch

    if (mode == 2) {
        // V: LDS tile [gn(d) 128][gm(s) 128], pitch 136; pack 4 row-consecutive vals (b64)
        for (int i = 0; i < 4; i++)
            for (int j = 0; j < 4; j++) {
                int gnl = wn + j * 16 + l15;
                float bv_ = bias[n0 + gnl];
                ushort4 pk;
                pk.x = f2bf(acc[i][j][0] + bv_);
                pk.y = f2bf(acc[i][j][1] + bv_);
                pk.z = f2bf(acc[i][j][2] + bv_);
                pk.w = f2bf(acc[i][j][3] + bv_);
                *(ushort4*)&Sm[gnl * 136 + wm + i * 16 + quad * 4] = pk;
            }
        __syncthreads();
        const int bb = m0 >> 11, sloc = m0 & 2047;
        for (int it = 0; it < 8; ++it) {
            int d = (tid >> 4) + it * 16;          // 0..127 local col
            int s8 = (tid & 15) * 8;
            float4 v = *(float4*)&Sm[d * 136 + s8];
            int h = (n0 + d) >> 6, dd = d & 63;
            *(float4*)&VtG[(size_t)(bb * 16 + h) * 131072 + (size_t)dd * 2048 + sloc + s8] = v;
        }
    } else {
        // Q/K: LDS tile [gm 128][gn 128], pitch 136; scalar dump, vector read-back
        for (int i = 0; i < 4; i++)
            for (int j = 0; j < 4; j++) {
                int gnl = wn + j * 16 + l15;
                float bv_ = bias[n0 + gnl];
                for (int r = 0; r < 4; r++) {
                    float v = acc[i][j][r] + bv_;
                    if (mode == 1) v *= QSCALE;
                    Sm[(wm + i * 16 + quad * 4 + r) * 136 + gnl] = f2bf(v);
                }
            }
        __syncthreads();
        ushort* dst = (mode == 1) ? Qb : Kb;
        for (int it = 0; it < 8; ++it) {
            int row = (tid >> 4) + it * 16, c = (tid & 15) * 8;
            *(float4*)&dst[(size_t)(m0 + row) * 1024 + n0 + c] = *(float4*)&Sm[row * 136 + c];
        }
    }
}

// Flash attention, no-max softmax (log2e folded into Q).
// Q:[4096,1024] bf16 (pre-scaled; groupwise s applied during staging from sb),
// K:[4096,1024] bf16, Vt:[32][64][2048] bf16, out fp32 [4096,1024].
// flat grid 512 (XCD-swizzled), block 256. One barrier/iter; async double-buffered K/V.
__launch_bounds__(256, 2)
__global__ void attn_kernel(const ushort* __restrict__ Q, const ushort* __restrict__ K,
                            const ushort* __restrict__ Vt, const float* __restrict__ sb,
                            float* __restrict__ out)
{
    __shared__ __align__(16) ushort Qs[128 * 72];
    __shared__ __align__(16) ushort Ps[128 * 72];
    __shared__ __align__(16) ushort Ks0[64 * 64];
    __shared__ __align__(16) ushort Ks1[64 * 64];
    __shared__ __align__(16) ushort Vs0[64 * 64];
    __shared__ __align__(16) ushort Vs1[64 * 64];

    const int tid = threadIdx.x, w = tid >> 6, lane = tid & 63;
    const int l15 = lane & 15, quad = lane >> 4;
    const int lrow = lane >> 3, lcol = (lane & 7) * 8;

    // XCD swizzle: same bh (same K/V) -> same XCD
    const int wid = blockIdx.x;
    const int r8 = wid & 7, jj = wid >> 3;
    const int bh = (jj & 3) * 8 + r8;    // 0..31
    const int qx = jj >> 2;              // 0..15
    const int b = bh >> 4, h = bh & 15;
    const int q0 = qx * 128;
    const size_t rowbase = (size_t)b * 2048;
    const int cbase = h * 64;

    // stage Q tile, applying groupwise scale s (s index for col n is n>>2)
    for (int it = 0; it < 4; ++it) {
        int l = tid + it * 256;
        int r = l >> 3, c = (l & 7) * 8;
        union { float4 f; ushort u[8]; } uu, oo;
        uu.f = *(const float4*)&Q[(rowbase + q0 + r) * 1024 + cbase + c];
        const float* sp = &sb[(rowbase + q0 + r) * 256 + ((cbase + c) >> 2)];
        float s0 = sp[0], s1 = sp[1];
        for (int j = 0; j < 4; j++) oo.u[j] = f2bf(bf2f(uu.u[j]) * s0);
        for (int j = 4; j < 8; j++) oo.u[j] = f2bf(bf2f(uu.u[j]) * s1);
        *(float4*)&Qs[r * 72 + c] = oo.f;
    }

    // prefetch K/V tile 0 into buffer 0
    for (int c = 0; c < 2; ++c) {
        int r = w * 16 + c * 8;
        async_load16(&K[(rowbase + r + lrow) * 1024 + cbase + lcol], &Ks0[r * 64]);
        async_load16(&Vt[(size_t)bh * 131072 + (size_t)(r + lrow) * 2048 + lcol], &Vs0[r * 64]);
    }

    float lsum[2][4];
    f32x4 o[2][4];
    for (int mt = 0; mt < 2; mt++) for (int r = 0; r < 4; r++) lsum[mt][r] = 0.f;
    for (int mt = 0; mt < 2; mt++) for (int nt = 0; nt < 4; nt++) o[mt][nt] = (f32x4){0.f, 0.f, 0.f, 0.f};

#define ATTN_STEP(KC, VC, KN, VN, KT, PREFETCH)                                                         \
    {                                                                                                   \
        __syncthreads(); /* vmcnt drained at barrier: tile KT resident; buf KN/VN free */               \
        if (PREFETCH) {                                                                                 \
            int nk = (KT) + 1;                                                                          \
            for (int c = 0; c < 2; ++c) {                                                               \
                int r = w * 16 + c * 8;                                                                 \
                async_load16(&K[(rowbase + nk * 64 + r + lrow) * 1024 + cbase + lcol], &KN[r * 64]);    \
                async_load16(&Vt[(size_t)bh * 131072 + (size_t)(r + lrow) * 2048 + nk * 64 + lcol],     \
                             &VN[r * 64]);                                                              \
            }                                                                                           \
        }                                                                                               \
        f32x4 sacc[2][4];                                                                               \
        for (int mt = 0; mt < 2; mt++)                                                                  \
            for (int nt = 0; nt < 4; nt++) sacc[mt][nt] = (f32x4){0.f, 0.f, 0.f, 0.f};                  \
        for (int kk = 0; kk < 64; kk += 32) {                                                           \
            bf16x8 a[2], bb[4];                                                                         \
            for (int mt = 0; mt < 2; mt++)                                                              \
                a[mt] = *(const bf16x8*)&Qs[(w * 32 + mt * 16 + l15) * 72 + kk + quad * 8];             \
            for (int nt = 0; nt < 4; nt++)                                                              \
                bb[nt] = *(const bf16x8*)&KC[(nt * 16 + l15) * 64 + kk + quad * 8];                     \
            for (int mt = 0; mt < 2; mt++)                                                              \
                for (int nt = 0; nt < 4; nt++)                                                          \
                    sacc[mt][nt] = __builtin_amdgcn_mfma_f32_16x16x32_bf16(a[mt], bb[nt],               \
                                                                           sacc[mt][nt], 0, 0, 0);     \
        }                                                                                               \
        for (int mt = 0; mt < 2; mt++)                                                                  \
            for (int nt = 0; nt < 4; nt++)                                                              \
                for (int r = 0; r < 4; r++) {                                                           \
                    float p = exp2f(sacc[mt][nt][r]);                                                   \
                    lsum[mt][r] += p;                                                                   \
                    Ps[(w * 32 + mt * 16 + quad * 4 + r) * 72 + nt * 16 + l15] = f2bf(p);               \
                }                                                                                       \
        /* Ps strip is wave-private: in-wave lgkmcnt ordering suffices, no barrier */                   \
        for (int kk = 0; kk < 64; kk += 32) {                                                           \
            bf16x8 a[2], bb[4];                                                                         \
            for (int mt = 0; mt < 2; mt++)                                                              \
                a[mt] = *(const bf16x8*)&Ps[(w * 32 + mt * 16 + l15) * 72 + kk + quad * 8];             \
            for (int nt = 0; nt < 4; nt++)                                                              \
                bb[nt] = *(const bf16x8*)&VC[(nt * 16 + l15) * 64 + kk + quad * 8];                     \
            for (int mt = 0; mt < 2; mt++)                                                              \
                for (int nt = 0; nt < 4; nt++)                                                          \
                    o[mt][nt] = __builtin_amdgcn_mfma_f32_16x16x32_bf16(a[mt], bb[nt],                  \
                                                                        o[mt][nt], 0, 0, 0);            \
        }                                                                                               \
    }

    for (int kt = 0; kt < 32; kt += 2) {
        ATTN_STEP(Ks0, Vs0, Ks1, Vs1, kt, 1);
        ATTN_STEP(Ks1, Vs1, Ks0, Vs0, kt + 1, (kt + 2 < 32));
    }
#undef ATTN_STEP

    for (int mt = 0; mt < 2; mt++)
        for (int r = 0; r < 4; r++) {
            float s = lsum[mt][r];
            for (int off = 1; off < 16; off <<= 1) s += __shfl_xor(s, off);
            lsum[mt][r] = s;
        }

    for (int mt = 0; mt < 2; mt++) {
        for (int r = 0; r < 4; r++) {
            float inv = 1.0f / lsum[mt][r];
            int q = q0 + w * 32 + mt * 16 + quad * 4 + r;
            size_t base = (rowbase + q) * 1024 + cbase;
            for (int nt = 0; nt < 4; nt++)
                out[base + nt * 16 + l15] = o[mt][nt][r] * inv;
        }
    }
}

extern "C" void kernel_launch(void* const* d_in, const int* in_sizes, int n_in,
                              void* d_out, int out_size, void* d_ws, size_t ws_size,
                              hipStream_t stream) {
    const float* hs = (const float*)d_in[0];
    const float* Wq = (const float*)d_in[1];
    const float* bq = (const float*)d_in[2];
    const float* Wk = (const float*)d_in[3];
    const float* bk = (const float*)d_in[4];
    const float* Wv = (const float*)d_in[5];
    const float* bv = (const float*)d_in[6];
    const float* Ws = (const float*)d_in[7];
    const float* bs = (const float*)d_in[8];
    float* outp = (float*)d_out;

    char* ws = (char*)d_ws;
    ushort* Qb    = (ushort*)(ws);                 //  8 MB
    ushort* Kb    = (ushort*)(ws + 8388608);       //  8 MB
    ushort* VtG   = (ushort*)(ws + 16777216);      //  8 MB (V transposed [bh][d][s])
    float*  sb    = (float* )(ws + 25165824);      //  4 MB
    ushort* hs_bf = (ushort*)(ws + 29360128);      //  8 MB
    ushort* Wq_bf = (ushort*)(ws + 37748736);      //  2 MB
    ushort* Wk_bf = (ushort*)(ws + 39845888);      //  2 MB
    ushort* Wv_bf = (ushort*)(ws + 41943040);      //  2 MB
    ushort* Ws_bf = (ushort*)(ws + 44040192);      // 0.5 MB -> total 44,564,480 B

    dim3 blk(256);
    cast_f32_bf16<<<dim3(2048), blk, 0, stream>>>(hs, hs_bf, 4194304);
    cast_f32_bf16<<<dim3(512),  blk, 0, stream>>>(Wq, Wq_bf, 1048576);
    cast_f32_bf16<<<dim3(512),  blk, 0, stream>>>(Wk, Wk_bf, 1048576);
    cast_f32_bf16<<<dim3(512),  blk, 0, stream>>>(Wv, Wv_bf, 1048576);
    cast_f32_bf16<<<dim3(128),  blk, 0, stream>>>(Ws, Ws_bf, 262144);

    fused_qkvs<<<dim3(832), blk, 0, stream>>>(hs_bf, Wq_bf, Wk_bf, Wv_bf, Ws_bf,
                                              bq, bk, bv, bs, Qb, Kb, VtG, sb);
    attn_kernel<<<dim3(512), blk, 0, stream>>>(Qb, Kb, VtG, sb, outp);
}

// Round 5
// 208.529 us; speedup vs baseline: 1.8700x; 1.0630x over previous
//
#include <hip/hip_runtime.h>

typedef short bf16x8 __attribute__((ext_vector_type(8)));
typedef float f32x4 __attribute__((ext_vector_type(4)));

__device__ inline float bf2f(ushort u) {
    unsigned v = ((unsigned)u) << 16;
    return __builtin_bit_cast(float, v);
}
__device__ inline ushort f2bf(float f) {
    unsigned u = __builtin_bit_cast(unsigned, f);
    u += 0x7fffu + ((u >> 16) & 1u);
    return (ushort)(u >> 16);
}
__device__ inline void async_load16(const ushort* g, ushort* l) {
    __builtin_amdgcn_global_load_lds((const __attribute__((address_space(1))) void*)g,
                                     (__attribute__((address_space(3))) void*)l, 16, 0, 0);
}

// fp32 -> bf16 cast, 8 elems/thread
__global__ void cast_f32_bf16(const float* __restrict__ src, ushort* __restrict__ dst, int n) {
    int i = (blockIdx.x * 256 + threadIdx.x) * 8;
    if (i >= n) return;
    float4 a = *(const float4*)(src + i);
    float4 b = *(const float4*)(src + i + 4);
    union { ushort u[8]; float4 v; } o;
    o.u[0] = f2bf(a.x); o.u[1] = f2bf(a.y); o.u[2] = f2bf(a.z); o.u[3] = f2bf(a.w);
    o.u[4] = f2bf(b.x); o.u[5] = f2bf(b.y); o.u[6] = f2bf(b.z); o.u[7] = f2bf(b.w);
    *(float4*)(dst + i) = o.v;
}

// Fused QKVS projection. X:[4096,1024] bf16, W*:[N,1024] bf16 row-major, bias fp32.
// xb 0-7 -> Q (scaled 0.125*log2e), 8-15 -> K, 16-23 -> V (transposed to VtG[bh][d][s]),
// 24-25 -> S (sigmoid -> fp32 sb). LDS tiles use XOR chunk swizzle:
// 16B chunk c of row r lives at slot c^(r&7) -> conflict-free ds_read_b128.
__launch_bounds__(256, 3)
__global__ void fused_qkvs(const ushort* __restrict__ X,
                           const ushort* __restrict__ Wq, const ushort* __restrict__ Wk,
                           const ushort* __restrict__ Wv, const ushort* __restrict__ Ws,
                           const float* __restrict__ bq, const float* __restrict__ bk,
                           const float* __restrict__ bv, const float* __restrict__ bs,
                           ushort* __restrict__ Qb, ushort* __restrict__ Kb,
                           ushort* __restrict__ VtG, float* __restrict__ sb)
{
    __shared__ __align__(16) ushort Sm[128 * 136];   // epilogue scratch; aliases As/Bs
    ushort* As = Sm;                 // 128 rows x 64 cols (swizzled)
    ushort* Bs = Sm + 128 * 64;

    const int tid = threadIdx.x, w = tid >> 6, lane = tid & 63;
    const int l15 = lane & 15, quad = lane >> 4;
    const int lrow = lane >> 3;
    const int gchunk = ((lane & 7) ^ lrow) * 8;   // swizzled global chunk for staging

    // XCD swizzle: same X tile -> same XCD (wid % 8)
    const int wid = blockIdx.x;
    const int r8 = wid & 7, jj = wid >> 3;
    const int by = (jj & 3) * 8 + r8;    // 0..31
    const int xb = jj >> 2;              // 0..25
    const int m0 = by * 128;

    const ushort* W; const float* bias; int n0, mode;
    if (xb < 8)       { W = Wq; bias = bq; n0 = xb * 128;        mode = 1; }
    else if (xb < 16) { W = Wk; bias = bk; n0 = (xb - 8) * 128;  mode = 0; }
    else if (xb < 24) { W = Wv; bias = bv; n0 = (xb - 16) * 128; mode = 2; }
    else              { W = Ws; bias = bs; n0 = (xb - 24) * 128; mode = 3; }

    const int wm = (w >> 1) * 64, wn = (w & 1) * 64;

    f32x4 acc[4][4];
    for (int i = 0; i < 4; i++) for (int j = 0; j < 4; j++) acc[i][j] = (f32x4){0.f, 0.f, 0.f, 0.f};

    for (int k0 = 0; k0 < 1024; k0 += 64) {
        __syncthreads();
        for (int c = 0; c < 4; ++c) {
            int r = w * 32 + c * 8;
            async_load16(&X[(size_t)(m0 + r + lrow) * 1024 + k0 + gchunk], &As[r * 64]);
            async_load16(&W[(size_t)(n0 + r + lrow) * 1024 + k0 + gchunk], &Bs[r * 64]);
        }
        __syncthreads();
        for (int kk = 0; kk < 64; kk += 32) {
            const int csw = quad + (kk >> 3);   // chunk index of this frag's 16B
            bf16x8 a[4], b[4];
            for (int i = 0; i < 4; i++)
                a[i] = *(const bf16x8*)&As[(wm + i * 16 + l15) * 64 + ((csw ^ (l15 & 7)) * 8)];
            for (int j = 0; j < 4; j++)
                b[j] = *(const bf16x8*)&Bs[(wn + j * 16 + l15) * 64 + ((csw ^ (l15 & 7)) * 8)];
            for (int i = 0; i < 4; i++)
                for (int j = 0; j < 4; j++)
                    acc[i][j] = __builtin_amdgcn_mfma_f32_16x16x32_bf16(a[i], b[j], acc[i][j], 0, 0, 0);
        }
    }

    const float QSCALE = 0.125f * 1.44269504f;  // 1/sqrt(D) and ln->log2 folded into Q

    if (mode == 3) {
        for (int i = 0; i < 4; i++)
            for (int j = 0; j < 4; j++) {
                int gn = n0 + wn + j * 16 + l15;
                float bv_ = bias[gn];
                for (int r = 0; r < 4; r++) {
                    int gm = m0 + wm + i * 16 + quad * 4 + r;
                    float v = acc[i][j][r] + bv_;
                    float sg = 1.0f / (1.0f + exp2f(-v * 1.44269504f));
                    sb[(size_t)gm * 256 + gn] = sg * 0.1f + 0.95f;
                }
            }
        return;
    }

    __syncthreads();  // main loop done with As/Bs; Sm becomes epilogue scratch

    if (mode == 2) {
        // V: LDS tile [gn(d) 128][gm(s) 128], pitch 136; pack 4 row-consecutive vals
        for (int i = 0; i < 4; i++)
            for (int j = 0; j < 4; j++) {
                int gnl = wn + j * 16 + l15;
                float bv_ = bias[n0 + gnl];
                ushort4 pk;
                pk.x = f2bf(acc[i][j][0] + bv_);
                pk.y = f2bf(acc[i][j][1] + bv_);
                pk.z = f2bf(acc[i][j][2] + bv_);
                pk.w = f2bf(acc[i][j][3] + bv_);
                *(ushort4*)&Sm[gnl * 136 + wm + i * 16 + quad * 4] = pk;
            }
        __syncthreads();
        const int bb = m0 >> 11, sloc = m0 & 2047;
        for (int it = 0; it < 8; ++it) {
            int d = (tid >> 4) + it * 16;
            int s8 = (tid & 15) * 8;
            float4 v = *(float4*)&Sm[d * 136 + s8];
            int h = (n0 + d) >> 6, dd = d & 63;
            *(float4*)&VtG[(size_t)(bb * 16 + h) * 131072 + (size_t)dd * 2048 + sloc + s8] = v;
        }
    } else {
        // Q/K: LDS tile [gm 128][gn 128], pitch 136
        for (int i = 0; i < 4; i++)
            for (int j = 0; j < 4; j++) {
                int gnl = wn + j * 16 + l15;
                float bv_ = bias[n0 + gnl];
                for (int r = 0; r < 4; r++) {
                    float v = acc[i][j][r] + bv_;
                    if (mode == 1) v *= QSCALE;
                    Sm[(wm + i * 16 + quad * 4 + r) * 136 + gnl] = f2bf(v);
                }
            }
        __syncthreads();
        ushort* dst = (mode == 1) ? Qb : Kb;
        for (int it = 0; it < 8; ++it) {
            int row = (tid >> 4) + it * 16, c = (tid & 15) * 8;
            *(float4*)&dst[(size_t)(m0 + row) * 1024 + n0 + c] = *(float4*)&Sm[row * 136 + c];
        }
    }
}

// Flash attention, no-max softmax (log2e folded into Q).
// Q:[4096,1024] bf16 (pre-scaled; groupwise s applied during staging from sb),
// K:[4096,1024] bf16, Vt:[32][64][2048] bf16, out fp32 [4096,1024].
// flat grid 512 (XCD-swizzled), block 256. K/V LDS tiles XOR-chunk-swizzled.
__launch_bounds__(256, 2)
__global__ void attn_kernel(const ushort* __restrict__ Q, const ushort* __restrict__ K,
                            const ushort* __restrict__ Vt, const float* __restrict__ sb,
                            float* __restrict__ out)
{
    __shared__ __align__(16) ushort Qs[128 * 72];
    __shared__ __align__(16) ushort Ps[128 * 72];
    __shared__ __align__(16) ushort Ks0[64 * 64];
    __shared__ __align__(16) ushort Ks1[64 * 64];
    __shared__ __align__(16) ushort Vs0[64 * 64];
    __shared__ __align__(16) ushort Vs1[64 * 64];

    const int tid = threadIdx.x, w = tid >> 6, lane = tid & 63;
    const int l15 = lane & 15, quad = lane >> 4;
    const int lrow = lane >> 3;
    const int gchunk = ((lane & 7) ^ lrow) * 8;   // swizzled global chunk for staging

    // XCD swizzle: same bh (same K/V) -> same XCD
    const int wid = blockIdx.x;
    const int r8 = wid & 7, jj = wid >> 3;
    const int bh = (jj & 3) * 8 + r8;    // 0..31
    const int qx = jj >> 2;              // 0..15
    const int b = bh >> 4, h = bh & 15;
    const int q0 = qx * 128;
    const size_t rowbase = (size_t)b * 2048;
    const int cbase = h * 64;

    // stage Q tile, applying groupwise scale s (s index for col n is n>>2)
    for (int it = 0; it < 4; ++it) {
        int l = tid + it * 256;
        int r = l >> 3, c = (l & 7) * 8;
        union { float4 f; ushort u[8]; } uu, oo;
        uu.f = *(const float4*)&Q[(rowbase + q0 + r) * 1024 + cbase + c];
        const float* sp = &sb[(rowbase + q0 + r) * 256 + ((cbase + c) >> 2)];
        float s0 = sp[0], s1 = sp[1];
        for (int j = 0; j < 4; j++) oo.u[j] = f2bf(bf2f(uu.u[j]) * s0);
        for (int j = 4; j < 8; j++) oo.u[j] = f2bf(bf2f(uu.u[j]) * s1);
        *(float4*)&Qs[r * 72 + c] = oo.f;
    }

    // prefetch K/V tile 0 into buffer 0 (swizzled)
    for (int c = 0; c < 2; ++c) {
        int r = w * 16 + c * 8;
        async_load16(&K[(rowbase + r + lrow) * 1024 + cbase + gchunk], &Ks0[r * 64]);
        async_load16(&Vt[(size_t)bh * 131072 + (size_t)(r + lrow) * 2048 + gchunk], &Vs0[r * 64]);
    }

    float lsum[2][4];
    f32x4 o[2][4];
    for (int mt = 0; mt < 2; mt++) for (int r = 0; r < 4; r++) lsum[mt][r] = 0.f;
    for (int mt = 0; mt < 2; mt++) for (int nt = 0; nt < 4; nt++) o[mt][nt] = (f32x4){0.f, 0.f, 0.f, 0.f};

#define ATTN_STEP(KC, VC, KN, VN, KT, PREFETCH)                                                         \
    {                                                                                                   \
        __syncthreads(); /* vmcnt drained at barrier: tile KT resident; buf KN/VN free */               \
        if (PREFETCH) {                                                                                 \
            int nk = (KT) + 1;                                                                          \
            for (int c = 0; c < 2; ++c) {                                                               \
                int r = w * 16 + c * 8;                                                                 \
                async_load16(&K[(rowbase + nk * 64 + r + lrow) * 1024 + cbase + gchunk], &KN[r * 64]);  \
                async_load16(&Vt[(size_t)bh * 131072 + (size_t)(r + lrow) * 2048 + nk * 64 + gchunk],   \
                             &VN[r * 64]);                                                              \
            }                                                                                           \
        }                                                                                               \
        f32x4 sacc[2][4];                                                                               \
        for (int mt = 0; mt < 2; mt++)                                                                  \
            for (int nt = 0; nt < 4; nt++) sacc[mt][nt] = (f32x4){0.f, 0.f, 0.f, 0.f};                  \
        for (int kk = 0; kk < 64; kk += 32) {                                                           \
            const int csw = ((quad + (kk >> 3)) ^ (l15 & 7)) * 8;                                       \
            bf16x8 a[2], bb[4];                                                                         \
            for (int mt = 0; mt < 2; mt++)                                                              \
                a[mt] = *(const bf16x8*)&Qs[(w * 32 + mt * 16 + l15) * 72 + kk + quad * 8];             \
            for (int nt = 0; nt < 4; nt++)                                                              \
                bb[nt] = *(const bf16x8*)&KC[(nt * 16 + l15) * 64 + csw];                               \
            for (int mt = 0; mt < 2; mt++)                                                              \
                for (int nt = 0; nt < 4; nt++)                                                          \
                    sacc[mt][nt] = __builtin_amdgcn_mfma_f32_16x16x32_bf16(a[mt], bb[nt],               \
                                                                           sacc[mt][nt], 0, 0, 0);     \
        }                                                                                               \
        for (int mt = 0; mt < 2; mt++)                                                                  \
            for (int nt = 0; nt < 4; nt++)                                                              \
                for (int r = 0; r < 4; r++) {                                                           \
                    float p = exp2f(sacc[mt][nt][r]);                                                   \
                    lsum[mt][r] += p;                                                                   \
                    Ps[(w * 32 + mt * 16 + quad * 4 + r) * 72 + nt * 16 + l15] = f2bf(p);               \
                }                                                                                       \
        /* Ps strip is wave-private: in-wave lgkmcnt ordering suffices, no barrier */                   \
        for (int kk = 0; kk < 64; kk += 32) {                                                           \
            const int csw = ((quad + (kk >> 3)) ^ (l15 & 7)) * 8;                                       \
            bf16x8 a[2], bb[4];                                                                         \
            for (int mt = 0; mt < 2; mt++)                                                              \
                a[mt] = *(const bf16x8*)&Ps[(w * 32 + mt * 16 + l15) * 72 + kk + quad * 8];             \
            for (int nt = 0; nt < 4; nt++)                                                              \
                bb[nt] = *(const bf16x8*)&VC[(nt * 16 + l15) * 64 + csw];                               \
            for (int mt = 0; mt < 2; mt++)                                                              \
                for (int nt = 0; nt < 4; nt++)                                                          \
                    o[mt][nt] = __builtin_amdgcn_mfma_f32_16x16x32_bf16(a[mt], bb[nt],                  \
                                                                        o[mt][nt], 0, 0, 0);            \
        }                                                                                               \
    }

    for (int kt = 0; kt < 32; kt += 2) {
        ATTN_STEP(Ks0, Vs0, Ks1, Vs1, kt, 1);
        ATTN_STEP(Ks1, Vs1, Ks0, Vs0, kt + 1, (kt + 2 < 32));
    }
#undef ATTN_STEP

    for (int mt = 0; mt < 2; mt++)
        for (int r = 0; r < 4; r++) {
            float s = lsum[mt][r];
            for (int off = 1; off < 16; off <<= 1) s += __shfl_xor(s, off);
            lsum[mt][r] = s;
        }

    for (int mt = 0; mt < 2; mt++) {
        for (int r = 0; r < 4; r++) {
            float inv = 1.0f / lsum[mt][r];
            int q = q0 + w * 32 + mt * 16 + quad * 4 + r;
            size_t base = (rowbase + q) * 1024 + cbase;
            for (int nt = 0; nt < 4; nt++)
                out[base + nt * 16 + l15] = o[mt][nt][r] * inv;
        }
    }
}

extern "C" void kernel_launch(void* const* d_in, const int* in_sizes, int n_in,
                              void* d_out, int out_size, void* d_ws, size_t ws_size,
                              hipStream_t stream) {
    const float* hs = (const float*)d_in[0];
    const float* Wq = (const float*)d_in[1];
    const float* bq = (const float*)d_in[2];
    const float* Wk = (const float*)d_in[3];
    const float* bk = (const float*)d_in[4];
    const float* Wv = (const float*)d_in[5];
    const float* bv = (const float*)d_in[6];
    const float* Ws = (const float*)d_in[7];
    const float* bs = (const float*)d_in[8];
    float* outp = (float*)d_out;

    char* ws = (char*)d_ws;
    ushort* Qb    = (ushort*)(ws);                 //  8 MB
    ushort* Kb    = (ushort*)(ws + 8388608);       //  8 MB
    ushort* VtG   = (ushort*)(ws + 16777216);      //  8 MB (V transposed [bh][d][s])
    float*  sb    = (float* )(ws + 25165824);      //  4 MB
    ushort* hs_bf = (ushort*)(ws + 29360128);      //  8 MB
    ushort* Wq_bf = (ushort*)(ws + 37748736);      //  2 MB
    ushort* Wk_bf = (ushort*)(ws + 39845888);      //  2 MB
    ushort* Wv_bf = (ushort*)(ws + 41943040);      //  2 MB
    ushort* Ws_bf = (ushort*)(ws + 44040192);      // 0.5 MB -> total 44,564,480 B

    dim3 blk(256);
    cast_f32_bf16<<<dim3(2048), blk, 0, stream>>>(hs, hs_bf, 4194304);
    cast_f32_bf16<<<dim3(512),  blk, 0, stream>>>(Wq, Wq_bf, 1048576);
    cast_f32_bf16<<<dim3(512),  blk, 0, stream>>>(Wk, Wk_bf, 1048576);
    cast_f32_bf16<<<dim3(512),  blk, 0, stream>>>(Wv, Wv_bf, 1048576);
    cast_f32_bf16<<<dim3(128),  blk, 0, stream>>>(Ws, Ws_bf, 262144);

    fused_qkvs<<<dim3(832), blk, 0, stream>>>(hs_bf, Wq_bf, Wk_bf, Wv_bf, Ws_bf,
                                              bq, bk, bv, bs, Qb, Kb, VtG, sb);
    attn_kernel<<<dim3(512), blk, 0, stream>>>(Qb, Kb, VtG, sb, outp);
}